// Round 2
// baseline (21028.551 us; speedup 1.0000x reference)
//
#include <hip/hip_runtime.h>

// STA-LSTM forward: B=2048, S=128, D=64, H1=H2=128, OUT=1
// 256 blocks x 512 threads (8 waves -> 2 waves/SIMD), each block owns 8 batch rows.
// Phase 1: spatial-attention LSTM (recurrent), H -> ws, alphas -> out
// Phase 2: betas + h_att (batched), betas -> out, h_att overwrites H in ws
// Phase 3: temporal LSTM (recurrent), y_pred -> out

#define BB 2048
#define SS 128
#define DD 64
#define HH 128
#define NG 512
#define M  8
#define NT 512

#define A_OFF    ((size_t)BB)
#define BETA_OFF ((size_t)BB + (size_t)SS*BB*DD)

__device__ __forceinline__ float sigf(float x){ return 1.0f/(1.0f + __expf(-x)); }
__device__ __forceinline__ float tanhx(float x){ return 1.0f - 2.0f/(1.0f + __expf(2.0f*x)); }

__device__ __forceinline__ float wmax64(float v){
#pragma unroll
  for (int m = 32; m; m >>= 1) v = fmaxf(v, __shfl_xor(v, m, 64));
  return v;
}
__device__ __forceinline__ float wsum64(float v){
#pragma unroll
  for (int m = 32; m; m >>= 1) v += __shfl_xor(v, m, 64);
  return v;
}

struct SM1 {              // phase 1: 30 KB
  float x[M][DD];
  float h[M][HH];
  float c[M][HH];
  float a[M][DD];
  float xw[M][DD];
  float g[M][NG];
};
struct SM2 {              // phase 2: 48 KB
  float A[32][HH];
  float tmp[32][SS];
  float bp[32][SS];
};
struct SM3 {              // phase 3: 28 KB
  float ha[M][HH];
  float lh[M][HH];
  float lc[M][HH];
  float g[M][NG];
  float yp[M];
};
union __align__(16) SMem { SM1 p1; SM2 p2; SM3 p3; };

__global__ __launch_bounds__(NT, 2) void sta_kernel(
    const float* __restrict__ X,
    const float* __restrict__ saW,  const float* __restrict__ saU,  const float* __restrict__ sab,
    const float* __restrict__ saWa, const float* __restrict__ saUa, const float* __restrict__ saba,
    const float* __restrict__ saVa,
    const float* __restrict__ taWa, const float* __restrict__ taba, const float* __restrict__ taVa,
    const float* __restrict__ taW,  const float* __restrict__ taU,  const float* __restrict__ tab,
    const float* __restrict__ taWy, const float* __restrict__ fcw,  const float* __restrict__ fcb,
    float* __restrict__ out, float* __restrict__ Hws)
{
  __shared__ SMem sm;
  const int tid = threadIdx.x;
  const int b0  = blockIdx.x * M;

  // ================= Phase 1: spatial-attention LSTM =================
  for (int idx = tid; idx < M*HH; idx += NT){
    int r = idx >> 7, j = idx & 127;
    sm.p1.h[r][j] = 0.f; sm.p1.c[r][j] = 0.f;
  }
  // stage x_0 (tid = r*64+d, one element per thread)
  {
    int r = tid >> 6, d = tid & 63;
    sm.p1.x[r][d] = X[(size_t)(b0+r)*SS*DD + d];
  }
  __syncthreads();

  for (int t = 0; t < SS; ++t){
    // a = tanh(x@saWa + [h,c]@saUa + saba)   (1 item/thread: row=wave, col=lane)
    {
      const int col = tid & 63;
      const int r   = tid >> 6;
      float acc = saba[col];
      for (int k = 0; k < DD; k += 4){
        float w0 = saWa[(k+0)*DD + col], w1 = saWa[(k+1)*DD + col];
        float w2 = saWa[(k+2)*DD + col], w3 = saWa[(k+3)*DD + col];
        float4 v = *(const float4*)&sm.p1.x[r][k];
        acc += w0*v.x + w1*v.y + w2*v.z + w3*v.w;
      }
      for (int k = 0; k < HH; k += 4){
        float w0 = saUa[(k+0)*DD + col], w1 = saUa[(k+1)*DD + col];
        float w2 = saUa[(k+2)*DD + col], w3 = saUa[(k+3)*DD + col];
        float4 v = *(const float4*)&sm.p1.h[r][k];
        acc += w0*v.x + w1*v.y + w2*v.z + w3*v.w;
      }
      for (int k = 0; k < HH; k += 4){
        float w0 = saUa[(HH+k+0)*DD + col], w1 = saUa[(HH+k+1)*DD + col];
        float w2 = saUa[(HH+k+2)*DD + col], w3 = saUa[(HH+k+3)*DD + col];
        float4 v = *(const float4*)&sm.p1.c[r][k];
        acc += w0*v.x + w1*v.y + w2*v.z + w3*v.w;
      }
      sm.p1.a[r][col] = tanhx(acc);
    }
    __syncthreads();

    // av = a@saVa ; alpha = softmax ; xw = alpha*x ; write alphas
    {
      const int col = tid & 63;
      const int r   = tid >> 6;
      float s = 0.f;
      for (int k = 0; k < DD; k += 4){
        float w0 = saVa[(k+0)*DD + col], w1 = saVa[(k+1)*DD + col];
        float w2 = saVa[(k+2)*DD + col], w3 = saVa[(k+3)*DD + col];
        float4 v = *(const float4*)&sm.p1.a[r][k];
        s += w0*v.x + w1*v.y + w2*v.z + w3*v.w;
      }
      float mm = wmax64(s);
      float e  = __expf(s - mm);
      float al = e * (1.0f / wsum64(e));
      out[A_OFF + (size_t)t*BB*DD + (size_t)(b0+r)*DD + col] = al;
      sm.p1.xw[r][col] = al * sm.p1.x[r][col];
    }
    __syncthreads();

    // gates = xw@saW + h@saU + sab   (1 col/thread, 8 rows in registers)
    {
      const int c0 = tid;
      float acc[M];
      const float bv = sab[c0];
#pragma unroll
      for (int r = 0; r < M; ++r) acc[r] = bv;
      for (int k = 0; k < DD; k += 4){
        float w0 = saW[(k+0)*NG + c0], w1 = saW[(k+1)*NG + c0];
        float w2 = saW[(k+2)*NG + c0], w3 = saW[(k+3)*NG + c0];
#pragma unroll
        for (int r = 0; r < M; ++r){
          float4 v = *(const float4*)&sm.p1.xw[r][k];
          acc[r] += w0*v.x + w1*v.y + w2*v.z + w3*v.w;
        }
      }
      for (int k = 0; k < HH; k += 4){
        float w0 = saU[(k+0)*NG + c0], w1 = saU[(k+1)*NG + c0];
        float w2 = saU[(k+2)*NG + c0], w3 = saU[(k+3)*NG + c0];
#pragma unroll
        for (int r = 0; r < M; ++r){
          float4 v = *(const float4*)&sm.p1.h[r][k];
          acc[r] += w0*v.x + w1*v.y + w2*v.z + w3*v.w;
        }
      }
#pragma unroll
      for (int r = 0; r < M; ++r) sm.p1.g[r][c0] = acc[r];
    }
    __syncthreads();

    // LSTM pointwise update + store H + stage x_{t+1}
    for (int idx = tid; idx < M*HH; idx += NT){
      int r = idx >> 7, j = idx & 127;
      float iv = sigf (sm.p1.g[r][j]);
      float fv = sigf (sm.p1.g[r][j +   HH]);
      float gv = tanhx(sm.p1.g[r][j + 2*HH]);
      float ov = sigf (sm.p1.g[r][j + 3*HH]);
      float cn = fv * sm.p1.c[r][j] + iv * gv;
      float hn = ov * tanhx(cn);
      sm.p1.c[r][j] = cn; sm.p1.h[r][j] = hn;
      Hws[(size_t)(b0+r)*SS*HH + (size_t)t*HH + j] = hn;
    }
    if (t + 1 < SS){
      int r = tid >> 6, d = tid & 63;
      sm.p1.x[r][d] = X[(size_t)(b0+r)*SS*DD + (size_t)(t+1)*DD + d];
    }
    __syncthreads();
  }

  // ================= Phase 2: betas + h_att (overwrites H in-place) =================
  for (int r = 0; r < M; ++r){
    float* Hrow = Hws + (size_t)(b0+r)*SS*HH;
    const int c  = tid & 127;
    const int th = tid >> 7;   // 0..3, owns rows th*8 .. th*8+7 of each 32-row chunk
    float hacc[32];
#pragma unroll
    for (int i = 0; i < 32; ++i) hacc[i] = 0.f;

#pragma unroll
    for (int ch = 0; ch < 4; ++ch){
      // stage 32 H rows into LDS (float4)
      for (int idx = tid; idx < 32*HH/4; idx += NT)
        ((float4*)sm.p2.A)[idx] = ((const float4*)(Hrow + (size_t)ch*32*HH))[idx];
      __syncthreads();

      // GEMM1: tmp = tanh(A @ taWa + taba)
      {
        float acc[8];
        const float bv = taba[c];
#pragma unroll
        for (int i = 0; i < 8; ++i) acc[i] = bv;
        for (int k = 0; k < HH; k += 4){
          float w0 = taWa[(k+0)*SS + c], w1 = taWa[(k+1)*SS + c];
          float w2 = taWa[(k+2)*SS + c], w3 = taWa[(k+3)*SS + c];
#pragma unroll
          for (int i = 0; i < 8; ++i){
            float4 v = *(const float4*)&sm.p2.A[th*8+i][k];
            acc[i] += w0*v.x + w1*v.y + w2*v.z + w3*v.w;
          }
        }
#pragma unroll
        for (int i = 0; i < 8; ++i) sm.p2.tmp[th*8+i][c] = tanhx(acc[i]);
      }
      __syncthreads();

      // GEMM2: bp = tmp @ taVa
      {
        float acc[8];
#pragma unroll
        for (int i = 0; i < 8; ++i) acc[i] = 0.f;
        for (int k = 0; k < SS; k += 4){
          float w0 = taVa[(k+0)*SS + c], w1 = taVa[(k+1)*SS + c];
          float w2 = taVa[(k+2)*SS + c], w3 = taVa[(k+3)*SS + c];
#pragma unroll
          for (int i = 0; i < 8; ++i){
            float4 v = *(const float4*)&sm.p2.tmp[th*8+i][k];
            acc[i] += w0*v.x + w1*v.y + w2*v.z + w3*v.w;
          }
        }
#pragma unroll
        for (int i = 0; i < 8; ++i) sm.p2.bp[th*8+i][c] = acc[i];
      }
      __syncthreads();

      // softmax rows of bp -> beta ; write betas out ; keep beta in LDS
      {
        const int wv = tid >> 6, lane = tid & 63;
#pragma unroll
        for (int it = 0; it < 4; ++it){
          int tl = wv + 8*it;
          float v0 = sm.p2.bp[tl][lane], v1 = sm.p2.bp[tl][lane+64];
          float mm = wmax64(fmaxf(v0, v1));
          float e0 = __expf(v0 - mm), e1 = __expf(v1 - mm);
          float inv = 1.0f / wsum64(e0 + e1);
          e0 *= inv; e1 *= inv;
          size_t bo = BETA_OFF + (size_t)(ch*32+tl)*BB*SS + (size_t)(b0+r)*SS;
          out[bo + lane]      = e0;
          out[bo + lane + 64] = e1;
          sm.p2.bp[tl][lane]      = e0;
          sm.p2.bp[tl][lane + 64] = e1;
        }
      }
      __syncthreads();

      // GEMM3: h_att(chunk rows) += beta @ Hrow   (Hrow streamed from L1/L2)
      for (int k = 0; k < SS; k += 4){
        float hv0 = Hrow[(size_t)(k+0)*HH + c], hv1 = Hrow[(size_t)(k+1)*HH + c];
        float hv2 = Hrow[(size_t)(k+2)*HH + c], hv3 = Hrow[(size_t)(k+3)*HH + c];
#pragma unroll
        for (int i = 0; i < 8; ++i){
          float4 bv = *(const float4*)&sm.p2.bp[th*8+i][k];
          hacc[ch*8+i] += bv.x*hv0 + bv.y*hv1 + bv.z*hv2 + bv.w*hv3;
        }
      }
    }
    __syncthreads();   // all Hrow reads complete before overwrite
#pragma unroll
    for (int ch = 0; ch < 4; ++ch)
#pragma unroll
      for (int i = 0; i < 8; ++i)
        Hrow[(size_t)(ch*32 + th*8 + i)*HH + c] = hacc[ch*8+i];
    __syncthreads();
  }

  // ================= Phase 3: temporal LSTM =================
  for (int idx = tid; idx < M*HH; idx += NT){
    int r = idx >> 7, j = idx & 127;
    sm.p3.lh[r][j] = 0.f; sm.p3.lc[r][j] = 0.f;
  }
  if (tid < M) sm.p3.yp[tid] = X[(size_t)(b0+tid)*SS*DD + (DD-1)];
  if (tid < M*HH/4)
    ((float4*)sm.p3.ha)[tid] = ((const float4*)(Hws + (size_t)b0*SS*HH))[0] , // placeholder overwritten below
    ((float4*)sm.p3.ha)[tid] = *((const float4*)(Hws) + ((size_t)(b0 + (tid>>5))*SS*HH)/4 + (tid & 31));
  __syncthreads();

  for (int t = 0; t < SS; ++t){
    // gates = h_att@taW + lh@taU + y_prev*taWy + tab   (1 col/thread, 8 rows)
    {
      const int c0 = tid;
      const float wy = taWy[c0];
      const float tb = tab[c0];
      float acc[M];
#pragma unroll
      for (int r = 0; r < M; ++r) acc[r] = tb + sm.p3.yp[r]*wy;
      for (int k = 0; k < HH; k += 4){
        float w0 = taW[(k+0)*NG + c0], w1 = taW[(k+1)*NG + c0];
        float w2 = taW[(k+2)*NG + c0], w3 = taW[(k+3)*NG + c0];
#pragma unroll
        for (int r = 0; r < M; ++r){
          float4 v = *(const float4*)&sm.p3.ha[r][k];
          acc[r] += w0*v.x + w1*v.y + w2*v.z + w3*v.w;
        }
      }
      for (int k = 0; k < HH; k += 4){
        float w0 = taU[(k+0)*NG + c0], w1 = taU[(k+1)*NG + c0];
        float w2 = taU[(k+2)*NG + c0], w3 = taU[(k+3)*NG + c0];
#pragma unroll
        for (int r = 0; r < M; ++r){
          float4 v = *(const float4*)&sm.p3.lh[r][k];
          acc[r] += w0*v.x + w1*v.y + w2*v.z + w3*v.w;
        }
      }
#pragma unroll
      for (int r = 0; r < M; ++r) sm.p3.g[r][c0] = acc[r];
    }
    __syncthreads();

    // LSTM pointwise update + stage h_att(t+1)
    for (int idx = tid; idx < M*HH; idx += NT){
      int r = idx >> 7, j = idx & 127;
      float iv = sigf (sm.p3.g[r][j]);
      float fv = sigf (sm.p3.g[r][j +   HH]);
      float gv = tanhx(sm.p3.g[r][j + 2*HH]);
      float ov = sigf (sm.p3.g[r][j + 3*HH]);
      float cn = fv * sm.p3.lc[r][j] + iv * gv;
      float hn = ov * tanhx(cn);
      sm.p3.lc[r][j] = cn; sm.p3.lh[r][j] = hn;
    }
    if (t + 1 < SS && tid < M*HH/4){
      int r = tid >> 5, q = tid & 31;   // 32 float4 per row of 128
      ((float4*)sm.p3.ha)[tid] =
        *(const float4*)(Hws + (size_t)(b0+r)*SS*HH + (size_t)(t+1)*HH + q*4);
    }
    __syncthreads();

    // y = lh @ fc_w^T + fc_b  (row=wave, 64 lanes)
    {
      const int r = tid >> 6, l = tid & 63;
      float p = sm.p3.lh[r][l] * fcw[l] + sm.p3.lh[r][l+64] * fcw[l+64];
      p = wsum64(p);
      if (l == 0) sm.p3.yp[r] = p + fcb[0];
    }
    __syncthreads();
  }

  if (tid < M) out[b0 + tid] = sm.p3.yp[tid];
}

extern "C" void kernel_launch(void* const* d_in, const int* in_sizes, int n_in,
                              void* d_out, int out_size, void* d_ws, size_t ws_size,
                              hipStream_t stream) {
  (void)in_sizes; (void)n_in; (void)out_size; (void)ws_size;
  const float* X    = (const float*)d_in[0];
  const float* saW  = (const float*)d_in[1];
  const float* saU  = (const float*)d_in[2];
  const float* sab  = (const float*)d_in[3];
  const float* saWa = (const float*)d_in[4];
  const float* saUa = (const float*)d_in[5];
  const float* saba = (const float*)d_in[6];
  const float* saVa = (const float*)d_in[7];
  const float* taWa = (const float*)d_in[8];
  // d_in[9] = ta_Ua: unused by the reference forward pass
  const float* taba = (const float*)d_in[10];
  const float* taVa = (const float*)d_in[11];
  const float* taW  = (const float*)d_in[12];
  const float* taU  = (const float*)d_in[13];
  const float* tab  = (const float*)d_in[14];
  const float* taWy = (const float*)d_in[15];
  const float* fcw  = (const float*)d_in[16];
  const float* fcb  = (const float*)d_in[17];
  float* out = (float*)d_out;
  float* Hws = (float*)d_ws;   // B*S*H1 floats = 128 MB: H, overwritten by h_att in phase 2

  hipLaunchKernelGGL(sta_kernel, dim3(BB / M), dim3(NT), 0, stream,
                     X, saW, saU, sab, saWa, saUa, saba, saVa,
                     taWa, taba, taVa, taW, taU, tab, taWy, fcw, fcb,
                     out, Hws);
}

// Round 3
// 6010.125 us; speedup vs baseline: 3.4989x; 3.4989x over previous
//
#include <hip/hip_runtime.h>

// STA-LSTM forward: B=2048, S=128, D=64, H1=H2=128, OUT=1
// Kernel A (256 blk x 512 thr, 1 blk/CU forced via 84KB LDS):
//   phase 1: spatial-attn LSTM (wave-k-sliced attention GEMMs, partials reduced in LDS)
//   phase 2: betas + h_att (overwrites H in ws)
// Kernel B (8192 blk x 512 thr): G0 = h_att @ ta_W + ta_b  (non-recurrent hoist)
// Kernel C (256 blk x 512 thr, 1 blk/CU): temporal LSTM; G0 path or direct fallback.

#define BB 2048
#define SS 128
#define DD 64
#define HH 128
#define NG 512
#define M  8
#define NT 512

#define A_OFF    ((size_t)BB)
#define BETA_OFF ((size_t)BB + (size_t)SS*BB*DD)
#define G0_BYTES ((size_t)BB*SS*NG*4)
#define H_BYTES  ((size_t)BB*SS*HH*4)

__device__ __forceinline__ float sigf(float x){ return 1.0f/(1.0f + __expf(-x)); }
__device__ __forceinline__ float tanhx(float x){ return 1.0f - 2.0f/(1.0f + __expf(2.0f*x)); }

__device__ __forceinline__ float wmax64(float v){
#pragma unroll
  for (int m = 32; m; m >>= 1) v = fmaxf(v, __shfl_xor(v, m, 64));
  return v;
}
__device__ __forceinline__ float wsum64(float v){
#pragma unroll
  for (int m = 32; m; m >>= 1) v += __shfl_xor(v, m, 64);
  return v;
}

struct SM1 {                       // 30 KB
  float x[M][DD];
  float h[M][HH];
  float c[M][HH];
  float a[M][DD];
  float xw[M][DD];
  float g[M][NG];
};
struct PH1 { SM1 s; float red[8*M*64]; };   // 30K + 16K = 46 KB
struct SM2 {                       // 48 KB
  float A[32][HH];
  float tmp[32][SS];
  float bp[32][SS];
};
// pad member forces sizeof(union)=84KB -> exactly 1 block/CU (160KB LDS pool)
union __align__(16) SMA { PH1 p1; SM2 p2; float pad[21504]; };

__global__ __launch_bounds__(NT, 2) void sta_ph12_kernel(
    const float* __restrict__ X,
    const float* __restrict__ saW,  const float* __restrict__ saU,  const float* __restrict__ sab,
    const float* __restrict__ saWa, const float* __restrict__ saUa, const float* __restrict__ saba,
    const float* __restrict__ saVa,
    const float* __restrict__ taWa, const float* __restrict__ taba, const float* __restrict__ taVa,
    float* __restrict__ out, float* __restrict__ Hws)
{
  __shared__ SMA sm;
  const int tid = threadIdx.x;
  const int b0  = blockIdx.x * M;
  const int w   = tid >> 6;      // wave 0..7
  const int l   = tid & 63;      // lane

  // ================= Phase 1: spatial-attention LSTM =================
  for (int idx = tid; idx < M*HH; idx += NT){
    int r = idx >> 7, j = idx & 127;
    sm.p1.s.h[r][j] = 0.f; sm.p1.s.c[r][j] = 0.f;
  }
  { // stage x_0 : tid = r*64+d
    int r = tid >> 6, d = tid & 63;
    sm.p1.s.x[r][d] = X[(size_t)(b0+r)*SS*DD + d];
  }
  __syncthreads();

  for (int t = 0; t < SS; ++t){
    // ---- attention GEMM1 partials: a_pre = x@saWa + [h,c]@saUa ----
    // wave w owns k-slices: x rows [w*8,w*8+8), h rows [w*16,+16), c rows [w*16,+16)
    {
      float pr[M];
#pragma unroll
      for (int r = 0; r < M; ++r) pr[r] = 0.f;
      { // x part
        const int kb = w*8;
#pragma unroll
        for (int q = 0; q < 2; ++q){
          const int k = kb + q*4;
          const float* wp = saWa + (size_t)k*DD + l;
          float w0 = wp[0], w1 = wp[DD], w2 = wp[2*DD], w3 = wp[3*DD];
#pragma unroll
          for (int r = 0; r < M; ++r){
            float4 v = *(const float4*)&sm.p1.s.x[r][k];
            pr[r] += w0*v.x + w1*v.y + w2*v.z + w3*v.w;
          }
        }
      }
      { // h part
        const int kb = w*16;
#pragma unroll
        for (int q = 0; q < 4; ++q){
          const int k = kb + q*4;
          const float* wp = saUa + (size_t)k*DD + l;
          float w0 = wp[0], w1 = wp[DD], w2 = wp[2*DD], w3 = wp[3*DD];
#pragma unroll
          for (int r = 0; r < M; ++r){
            float4 v = *(const float4*)&sm.p1.s.h[r][k];
            pr[r] += w0*v.x + w1*v.y + w2*v.z + w3*v.w;
          }
        }
      }
      { // c part (saUa rows HH..2HH)
        const int kb = w*16;
#pragma unroll
        for (int q = 0; q < 4; ++q){
          const int k = kb + q*4;
          const float* wp = saUa + (size_t)(HH + k)*DD + l;
          float w0 = wp[0], w1 = wp[DD], w2 = wp[2*DD], w3 = wp[3*DD];
#pragma unroll
          for (int r = 0; r < M; ++r){
            float4 v = *(const float4*)&sm.p1.s.c[r][k];
            pr[r] += w0*v.x + w1*v.y + w2*v.z + w3*v.w;
          }
        }
      }
#pragma unroll
      for (int r = 0; r < M; ++r) sm.p1.red[w*(M*64) + r*64 + l] = pr[r];
    }
    __syncthreads();

    // ---- reduce + bias + tanh -> a ----
    {
      const int r = w, col = l;   // wave r handles row r
      float s = saba[col];
#pragma unroll
      for (int u = 0; u < 8; ++u) s += sm.p1.red[u*(M*64) + r*64 + col];
      sm.p1.s.a[r][col] = tanhx(s);
    }
    __syncthreads();

    // ---- attention GEMM2 partials: av = a @ saVa (wave w: k in [w*8,w*8+8)) ----
    {
      float pr[M];
#pragma unroll
      for (int r = 0; r < M; ++r) pr[r] = 0.f;
      const int kb = w*8;
#pragma unroll
      for (int q = 0; q < 2; ++q){
        const int k = kb + q*4;
        const float* wp = saVa + (size_t)k*DD + l;
        float w0 = wp[0], w1 = wp[DD], w2 = wp[2*DD], w3 = wp[3*DD];
#pragma unroll
        for (int r = 0; r < M; ++r){
          float4 v = *(const float4*)&sm.p1.s.a[r][k];
          pr[r] += w0*v.x + w1*v.y + w2*v.z + w3*v.w;
        }
      }
#pragma unroll
      for (int r = 0; r < M; ++r) sm.p1.red[w*(M*64) + r*64 + l] = pr[r];
    }
    __syncthreads();

    // ---- reduce2 + softmax + alphas out + xw ----
    {
      const int r = w, col = l;
      float s = 0.f;
#pragma unroll
      for (int u = 0; u < 8; ++u) s += sm.p1.red[u*(M*64) + r*64 + col];
      float mm = wmax64(s);
      float e  = __expf(s - mm);
      float al = e * (1.0f / wsum64(e));
      out[A_OFF + (size_t)t*BB*DD + (size_t)(b0+r)*DD + col] = al;
      sm.p1.s.xw[r][col] = al * sm.p1.s.x[r][col];
    }
    __syncthreads();

    // ---- gates = xw@saW + h@saU + sab  (1 col/thread, 8 rows) ----
    {
      const int c0 = tid;
      float acc[M];
      const float bv = sab[c0];
#pragma unroll
      for (int r = 0; r < M; ++r) acc[r] = bv;
      for (int k = 0; k < DD; k += 4){
        const float* wp = saW + (size_t)k*NG + c0;
        float w0 = wp[0], w1 = wp[NG], w2 = wp[2*NG], w3 = wp[3*NG];
#pragma unroll
        for (int r = 0; r < M; ++r){
          float4 v = *(const float4*)&sm.p1.s.xw[r][k];
          acc[r] += w0*v.x + w1*v.y + w2*v.z + w3*v.w;
        }
      }
      for (int k = 0; k < HH; k += 4){
        const float* wp = saU + (size_t)k*NG + c0;
        float w0 = wp[0], w1 = wp[NG], w2 = wp[2*NG], w3 = wp[3*NG];
#pragma unroll
        for (int r = 0; r < M; ++r){
          float4 v = *(const float4*)&sm.p1.s.h[r][k];
          acc[r] += w0*v.x + w1*v.y + w2*v.z + w3*v.w;
        }
      }
#pragma unroll
      for (int r = 0; r < M; ++r) sm.p1.s.g[r][c0] = acc[r];
    }
    __syncthreads();

    // ---- LSTM pointwise + store H + stage x_{t+1} ----
    for (int idx = tid; idx < M*HH; idx += NT){
      int r = idx >> 7, j = idx & 127;
      float iv = sigf (sm.p1.s.g[r][j]);
      float fv = sigf (sm.p1.s.g[r][j +   HH]);
      float gv = tanhx(sm.p1.s.g[r][j + 2*HH]);
      float ov = sigf (sm.p1.s.g[r][j + 3*HH]);
      float cn = fv * sm.p1.s.c[r][j] + iv * gv;
      float hn = ov * tanhx(cn);
      sm.p1.s.c[r][j] = cn; sm.p1.s.h[r][j] = hn;
      Hws[(size_t)(b0+r)*SS*HH + (size_t)t*HH + j] = hn;
    }
    if (t + 1 < SS){
      int r = tid >> 6, d = tid & 63;
      sm.p1.s.x[r][d] = X[(size_t)(b0+r)*SS*DD + (size_t)(t+1)*DD + d];
    }
    __syncthreads();
  }

  // ================= Phase 2: betas + h_att (overwrites H in-place) =================
  for (int r = 0; r < M; ++r){
    float* Hrow = Hws + (size_t)(b0+r)*SS*HH;
    const int c  = tid & 127;
    const int th = tid >> 7;   // 0..3, owns rows th*8..th*8+7 of each 32-row chunk
    float hacc[32];
#pragma unroll
    for (int i = 0; i < 32; ++i) hacc[i] = 0.f;

#pragma unroll
    for (int ch = 0; ch < 4; ++ch){
      for (int idx = tid; idx < 32*HH/4; idx += NT)
        ((float4*)sm.p2.A)[idx] = ((const float4*)(Hrow + (size_t)ch*32*HH))[idx];
      __syncthreads();

      { // GEMM1: tmp = tanh(A @ taWa + taba)
        float acc[8];
        const float bv = taba[c];
#pragma unroll
        for (int i = 0; i < 8; ++i) acc[i] = bv;
        for (int k = 0; k < HH; k += 4){
          const float* wp = taWa + (size_t)k*SS + c;
          float w0 = wp[0], w1 = wp[SS], w2 = wp[2*SS], w3 = wp[3*SS];
#pragma unroll
          for (int i = 0; i < 8; ++i){
            float4 v = *(const float4*)&sm.p2.A[th*8+i][k];
            acc[i] += w0*v.x + w1*v.y + w2*v.z + w3*v.w;
          }
        }
#pragma unroll
        for (int i = 0; i < 8; ++i) sm.p2.tmp[th*8+i][c] = tanhx(acc[i]);
      }
      __syncthreads();

      { // GEMM2: bp = tmp @ taVa
        float acc[8];
#pragma unroll
        for (int i = 0; i < 8; ++i) acc[i] = 0.f;
        for (int k = 0; k < SS; k += 4){
          const float* wp = taVa + (size_t)k*SS + c;
          float w0 = wp[0], w1 = wp[SS], w2 = wp[2*SS], w3 = wp[3*SS];
#pragma unroll
          for (int i = 0; i < 8; ++i){
            float4 v = *(const float4*)&sm.p2.tmp[th*8+i][k];
            acc[i] += w0*v.x + w1*v.y + w2*v.z + w3*v.w;
          }
        }
#pragma unroll
        for (int i = 0; i < 8; ++i) sm.p2.bp[th*8+i][c] = acc[i];
      }
      __syncthreads();

      { // softmax rows of bp -> beta ; write betas ; keep beta in LDS
        const int wv = tid >> 6, lane = tid & 63;
#pragma unroll
        for (int it = 0; it < 4; ++it){
          int tl = wv + 8*it;
          float v0 = sm.p2.bp[tl][lane], v1 = sm.p2.bp[tl][lane+64];
          float mm = wmax64(fmaxf(v0, v1));
          float e0 = __expf(v0 - mm), e1 = __expf(v1 - mm);
          float inv = 1.0f / wsum64(e0 + e1);
          e0 *= inv; e1 *= inv;
          size_t bo = BETA_OFF + (size_t)(ch*32+tl)*BB*SS + (size_t)(b0+r)*SS;
          out[bo + lane]      = e0;
          out[bo + lane + 64] = e1;
          sm.p2.bp[tl][lane]      = e0;
          sm.p2.bp[tl][lane + 64] = e1;
        }
      }
      __syncthreads();

      // GEMM3: h_att(chunk rows) += beta @ Hrow
      for (int k = 0; k < SS; k += 4){
        const float* hp = Hrow + (size_t)k*HH + c;
        float hv0 = hp[0], hv1 = hp[HH], hv2 = hp[2*HH], hv3 = hp[3*HH];
#pragma unroll
        for (int i = 0; i < 8; ++i){
          float4 bv = *(const float4*)&sm.p2.bp[th*8+i][k];
          hacc[ch*8+i] += bv.x*hv0 + bv.y*hv1 + bv.z*hv2 + bv.w*hv3;
        }
      }
    }
    __syncthreads();   // all Hrow reads complete before overwrite
#pragma unroll
    for (int ch = 0; ch < 4; ++ch)
#pragma unroll
      for (int i = 0; i < 8; ++i)
        Hrow[(size_t)(ch*32 + th*8 + i)*HH + c] = hacc[ch*8+i];
    __syncthreads();
  }
}

// ============ Kernel B: G0[b,t,:] = h_att[b,t,:] @ ta_W + ta_b ============
#define BROWS 32
__global__ __launch_bounds__(NT, 2) void g0_kernel(
    const float* __restrict__ Ha, const float* __restrict__ taW,
    const float* __restrict__ tab, float* __restrict__ G0)
{
  __shared__ float hs[BROWS][HH];   // 16 KB
  const int tid = threadIdx.x;
  const size_t row0 = (size_t)blockIdx.x * BROWS;
  for (int idx = tid; idx < BROWS*HH/4; idx += NT)
    ((float4*)hs)[idx] = ((const float4*)(Ha + row0*HH))[idx];
  __syncthreads();
  const int c = tid;
  float acc[BROWS];
  const float tb = tab[c];
#pragma unroll
  for (int r = 0; r < BROWS; ++r) acc[r] = tb;
  for (int k = 0; k < HH; k += 4){
    const float* wp = taW + (size_t)k*NG + c;
    float w0 = wp[0], w1 = wp[NG], w2 = wp[2*NG], w3 = wp[3*NG];
#pragma unroll
    for (int r = 0; r < BROWS; ++r){
      float4 v = *(const float4*)&hs[r][k];
      acc[r] += w0*v.x + w1*v.y + w2*v.z + w3*v.w;
    }
  }
#pragma unroll
  for (int r = 0; r < BROWS; ++r) G0[(row0 + r)*NG + c] = acc[r];
}

// ============ Kernel C: temporal LSTM ============
union __align__(16) SMC {
  struct {
    float ha[M][HH];
    float lh[M][HH];
    float lc[M][HH];
    float g[M][NG];
    float yp[M];
  } s;
  float pad[21504];   // force 84KB -> 1 block/CU
};

template<int UG>
__global__ __launch_bounds__(NT, 2) void sta_ph3_kernel(
    const float* __restrict__ X, const float* __restrict__ Ha,
    const float* __restrict__ G0,
    const float* __restrict__ taW, const float* __restrict__ taU,
    const float* __restrict__ tab, const float* __restrict__ taWy,
    const float* __restrict__ fcw, const float* __restrict__ fcb,
    float* __restrict__ out)
{
  __shared__ SMC sm;
  const int tid = threadIdx.x;
  const int b0  = blockIdx.x * M;

  for (int idx = tid; idx < M*HH; idx += NT){
    int r = idx >> 7, j = idx & 127;
    sm.s.lh[r][j] = 0.f; sm.s.lc[r][j] = 0.f;
  }
  if (tid < M) sm.s.yp[tid] = X[(size_t)(b0+tid)*SS*DD + (DD-1)];
  if (!UG && tid < M*HH/4){
    int r = tid >> 5, q = tid & 31;
    ((float4*)sm.s.ha)[tid] = *(const float4*)(Ha + (size_t)(b0+r)*SS*HH + q*4);
  }
  __syncthreads();

  for (int t = 0; t < SS; ++t){
    // ---- gates ----
    {
      const int c0 = tid;
      const float wy = taWy[c0];
      float g0v[M];
      if (UG){
#pragma unroll
        for (int r = 0; r < M; ++r)
          g0v[r] = G0[((size_t)(b0+r)*SS + t)*NG + c0];   // issued early, used after k-loop
      }
      float acc[M];
      if (UG){
#pragma unroll
        for (int r = 0; r < M; ++r) acc[r] = sm.s.yp[r]*wy;
      } else {
        const float tb = tab[c0];
#pragma unroll
        for (int r = 0; r < M; ++r) acc[r] = tb + sm.s.yp[r]*wy;
        for (int k = 0; k < HH; k += 4){
          const float* wp = taW + (size_t)k*NG + c0;
          float w0 = wp[0], w1 = wp[NG], w2 = wp[2*NG], w3 = wp[3*NG];
#pragma unroll
          for (int r = 0; r < M; ++r){
            float4 v = *(const float4*)&sm.s.ha[r][k];
            acc[r] += w0*v.x + w1*v.y + w2*v.z + w3*v.w;
          }
        }
      }
      for (int k = 0; k < HH; k += 4){
        const float* wp = taU + (size_t)k*NG + c0;
        float w0 = wp[0], w1 = wp[NG], w2 = wp[2*NG], w3 = wp[3*NG];
#pragma unroll
        for (int r = 0; r < M; ++r){
          float4 v = *(const float4*)&sm.s.lh[r][k];
          acc[r] += w0*v.x + w1*v.y + w2*v.z + w3*v.w;
        }
      }
      if (UG){
#pragma unroll
        for (int r = 0; r < M; ++r) acc[r] += g0v[r];
      }
#pragma unroll
      for (int r = 0; r < M; ++r) sm.s.g[r][c0] = acc[r];
    }
    __syncthreads();

    // ---- pointwise + (fallback) stage ha(t+1) ----
    for (int idx = tid; idx < M*HH; idx += NT){
      int r = idx >> 7, j = idx & 127;
      float iv = sigf (sm.s.g[r][j]);
      float fv = sigf (sm.s.g[r][j +   HH]);
      float gv = tanhx(sm.s.g[r][j + 2*HH]);
      float ov = sigf (sm.s.g[r][j + 3*HH]);
      float cn = fv * sm.s.lc[r][j] + iv * gv;
      float hn = ov * tanhx(cn);
      sm.s.lc[r][j] = cn; sm.s.lh[r][j] = hn;
    }
    if (!UG && t + 1 < SS && tid < M*HH/4){
      int r = tid >> 5, q = tid & 31;
      ((float4*)sm.s.ha)[tid] =
        *(const float4*)(Ha + (size_t)(b0+r)*SS*HH + (size_t)(t+1)*HH + q*4);
    }
    __syncthreads();

    // ---- y = lh @ fc_w^T + fc_b (wave r, 64 lanes) ----
    {
      const int r = tid >> 6, l = tid & 63;
      float p = sm.s.lh[r][l] * fcw[l] + sm.s.lh[r][l+64] * fcw[l+64];
      p = wsum64(p);
      if (l == 0) sm.s.yp[r] = p + fcb[0];
    }
    __syncthreads();
  }

  if (tid < M) out[b0 + tid] = sm.s.yp[tid];
}

extern "C" void kernel_launch(void* const* d_in, const int* in_sizes, int n_in,
                              void* d_out, int out_size, void* d_ws, size_t ws_size,
                              hipStream_t stream) {
  (void)in_sizes; (void)n_in; (void)out_size;
  const float* X    = (const float*)d_in[0];
  const float* saW  = (const float*)d_in[1];
  const float* saU  = (const float*)d_in[2];
  const float* sab  = (const float*)d_in[3];
  const float* saWa = (const float*)d_in[4];
  const float* saUa = (const float*)d_in[5];
  const float* saba = (const float*)d_in[6];
  const float* saVa = (const float*)d_in[7];
  const float* taWa = (const float*)d_in[8];
  // d_in[9] = ta_Ua: unused by the reference forward pass
  const float* taba = (const float*)d_in[10];
  const float* taVa = (const float*)d_in[11];
  const float* taW  = (const float*)d_in[12];
  const float* taU  = (const float*)d_in[13];
  const float* tab  = (const float*)d_in[14];
  const float* taWy = (const float*)d_in[15];
  const float* fcw  = (const float*)d_in[16];
  const float* fcb  = (const float*)d_in[17];
  float* out = (float*)d_out;
  float* Hws = (float*)d_ws;                       // B*S*H floats: H, then h_att
  float* G0  = Hws + (size_t)BB*SS*HH;             // B*S*4H2 floats (if ws allows)
  const bool useG0 = ws_size >= (H_BYTES + G0_BYTES);

  hipLaunchKernelGGL(sta_ph12_kernel, dim3(BB / M), dim3(NT), 0, stream,
                     X, saW, saU, sab, saWa, saUa, saba, saVa,
                     taWa, taba, taVa, out, Hws);
  if (useG0){
    hipLaunchKernelGGL(g0_kernel, dim3((BB*SS)/BROWS), dim3(NT), 0, stream,
                       Hws, taW, tab, G0);
    hipLaunchKernelGGL((sta_ph3_kernel<1>), dim3(BB / M), dim3(NT), 0, stream,
                       X, Hws, G0, taW, taU, tab, taWy, fcw, fcb, out);
  } else {
    hipLaunchKernelGGL((sta_ph3_kernel<0>), dim3(BB / M), dim3(NT), 0, stream,
                       X, Hws, G0, taW, taU, tab, taWy, fcw, fcb, out);
  }
}